// Round 7
// baseline (176.485 us; speedup 1.0000x reference)
//
#include <hip/hip_runtime.h>
#include <hip/hip_bf16.h>

#define Bn 8
#define Nn 207
#define Tn 12
#define Cn 64
#define Ln (Nn*Tn)      // 2484
#define LP 2496         // padded to 64
#define NT 39           // LP/64
#define NRB 156         // 16-row attn blocks per batch (LP/16)

typedef unsigned int u32;
typedef unsigned short u16;
typedef _Float16 f16;
typedef __fp16 h16;
typedef __attribute__((ext_vector_type(2))) __fp16 h16x2;
typedef __attribute__((ext_vector_type(4))) __fp16 h16x4;
typedef __attribute__((ext_vector_type(4))) float floatx4;

#define LOG2E 1.44269504088896f

__device__ __forceinline__ u16 f2h(float f) { f16 h = (f16)f; return *(u16*)&h; }
__device__ __forceinline__ float h2f_lo(u32 u) { u16 x = (u16)u;        f16 h = *(f16*)&x; return (float)h; }
__device__ __forceinline__ float h2f_hi(u32 u) { u16 x = (u16)(u >> 16); f16 h = *(f16*)&x; return (float)h; }

// ---------------- ws layout ----------------
#define W_PW   0            // u32 [k][cig][j][co] packed {wA,wB} : 12288 u32
#define U_WVT  24576        // f16 [o][c] 4096 u16
#define F_WK   14336        // fp32 [c][8] 512 (float offsets)
#define F_WQ   14848        // fp32 [c][8] 512  (pre-scaled by log2(e))
#define U_K    30720        // f16 [Bn][LP][8]   159744 u16 (pad rows zeroed)
#define U_Q    190464       // f16 [Bn][LP][8]   159744 u16 (log2e-scaled q)
// hT swizzled to PV A-frag order: [b][tile][ss][cs][rm*4+quad][i]
#define U_HT   350208       // f16 [Bn][NT][16][256] 1277952 u16 (tail zeroed)

// ---------------- kernel 0: weight pack + pad zeroing ----------
__global__ __launch_bounds__(256) void prep_kernel(
    const float* __restrict__ wA, const float* __restrict__ wB,
    const float* __restrict__ wq, const float* __restrict__ wk,
    const float* __restrict__ wv, float* __restrict__ ws)
{
    u16* wsu = (u16*)ws;
    u32* wsw = (u32*)ws;
    int idx = blockIdx.x * 256 + threadIdx.x;
    if (idx < 12288) {
        int co = idx & 63, j = (idx >> 6) & 7, cig = (idx >> 9) & 7, k = idx >> 12;
        int src = (co*64 + cig*8 + j)*3 + k;
        wsw[W_PW + idx] = (u32)f2h(wA[src]) | ((u32)f2h(wB[src]) << 16);
    } else if (idx < 16384) {
        int j = idx - 12288;
        wsu[U_WVT + j] = f2h(wv[j]);
    } else if (idx < 16896) {
        int j = idx - 16384; int o = j & 7, c = j >> 3;
        ws[F_WK + j] = wk[o*Cn + c];
    } else if (idx < 17408) {
        int j = idx - 16896; int o = j & 7, c = j >> 3;
        ws[F_WQ + j] = wq[o*Cn + c] * LOG2E;      // fold log2(e): exp(s) == exp2(s')
    } else if (idx < 18944) {
        int j = idx - 17408;            // zero k/q pad rows Ln..LP-1
        int b = j / 192, rem = j - b*192;
        int which = rem / 96, rr = rem - which*96;
        wsu[(which ? U_Q : U_K) + (size_t)b*LP*8 + Ln*8 + rr] = 0;
    } else if (idx < 25088) {
        int j = idx - 18944;            // zero hT tail: tile 38, mloc 52..63 (swizzled)
        int b = j / 768, rem = j - b*768;
        int c = rem / 12, mm = 52 + (rem - c*12);
        int ss = mm >> 4, q = (mm >> 2) & 3, i = mm & 3;
        int cs = c >> 4, rm = c & 15;
        wsu[U_HT + (size_t)b*NT*4096 + ((38*16 + ss*4 + cs)*256 + (rm*4 + q)*4 + i)] = 0;
    }
}

// ---------------- kernel 1: conv + GLU + k/q proj + swizzled hT ------------
// one block per (b, n), XCD-affine: b = blockIdx & 7.
// Weights staged in HALVES (cig 0-3 then 4-7): 24 KB buffer instead of 48.
// NOTE: launch_bounds must stay (256,2) — (.,4) force-caps VGPR to 64 and
// spills catastrophically (R4: 305us, R5: 170us, WRITE 446MB).
__global__ __launch_bounds__(256, 2) void conv_k_kernel(
    const float* __restrict__ X,
    const float* __restrict__ bA, const float* __restrict__ bB,
    const float* __restrict__ bk, const float* __restrict__ bq,
    float* __restrict__ ws, float* __restrict__ out)
{
    __shared__ u32   w_s[6144];        // 24 KB: [k][cl(4)][j][co] one cig-half
    __shared__ float xs[Tn*Cn];        // 3 KB
    __shared__ float hs[Tn*Cn];        // 3 KB
    __shared__ float wkq_s[1024];      // 4 KB
    int b = blockIdx.x & 7;            // XCD-affinity swizzle (8 XCDs)
    int n = blockIdx.x >> 3;
    int tid = threadIdx.x;

    const u32* wsw = (const u32*)ws;
    // stage weight half 0 (cig 0..3): 1536 uint4
    #pragma unroll
    for (int i = 0; i < 6; ++i) {
        int d4 = i*256 + tid;
        int co4 = d4 & 15, j = (d4 >> 4) & 7, cl = (d4 >> 7) & 3, k = d4 >> 9;
        ((uint4*)w_s)[d4] = ((const uint4*)(wsw + W_PW))[((k*8 + cl)*8 + j)*16 + co4];
    }
    const float* Xp = X + (size_t)(b*Nn + n)*Tn*Cn;
    if (tid < 192)
        ((float4*)xs)[tid] = ((const float4*)Xp)[tid];
    ((float4*)wkq_s)[tid] = ((const float4*)(ws + F_WK))[tid];
    __syncthreads();                   // half0 + xs ready

    int co = tid & 63;
    int tg = tid >> 6;                 // rows t = 3tg..3tg+2
    float aA[3] = {bA[co], bA[co], bA[co]};
    float aB[3] = {bB[co], bB[co], bB[co]};
    int tb = tg*3 - 2;

    #pragma unroll 1
    for (int half = 0; half < 2; ++half) {
        #pragma unroll 1               // DO NOT unroll: full unroll spills xr -> scratch
        for (int cl = 0; cl < 4; ++cl) {
            int cig = half*4 + cl;
            float xr[5][8];
            #pragma unroll
            for (int d = 0; d < 5; ++d) {
                int tp = tb + d;
                if (tp >= 0) {
                    float4 xa = *(const float4*)(xs + tp*Cn + cig*8);
                    float4 xb = *(const float4*)(xs + tp*Cn + cig*8 + 4);
                    xr[d][0]=xa.x; xr[d][1]=xa.y; xr[d][2]=xa.z; xr[d][3]=xa.w;
                    xr[d][4]=xb.x; xr[d][5]=xb.y; xr[d][6]=xb.z; xr[d][7]=xb.w;
                } else {
                    #pragma unroll
                    for (int j = 0; j < 8; ++j) xr[d][j] = 0.f;
                }
            }
            #pragma unroll
            for (int k = 0; k < 3; ++k) {
                #pragma unroll
                for (int j = 0; j < 8; ++j) {
                    u32 p = w_s[((k*4 + cl)*8 + j)*64 + co];
                    float wa = h2f_lo(p), wb = h2f_hi(p);
                    #pragma unroll
                    for (int tt = 0; tt < 3; ++tt) {
                        aA[tt] += xr[tt + k][j] * wa;
                        aB[tt] += xr[tt + k][j] * wb;
                    }
                }
            }
        }
        if (half == 0) {
            __syncthreads();           // all reads of half0 done
            #pragma unroll
            for (int i = 0; i < 6; ++i) {  // stage half 1 (cig 4..7)
                int d4 = i*256 + tid;
                int co4 = d4 & 15, j = (d4 >> 4) & 7, cl = (d4 >> 7) & 3, k = d4 >> 9;
                ((uint4*)w_s)[d4] =
                    ((const uint4*)(wsw + W_PW))[((k*8 + 4 + cl)*8 + j)*16 + co4];
            }
            __syncthreads();           // half1 ready
        }
    }

    #pragma unroll
    for (int tt = 0; tt < 3; ++tt) {
        int t = tg*3 + tt;
        float hv = aA[tt] * (1.f / (1.f + __expf(-aB[tt])));
        hs[t*Cn + co] = hv;
        out[((size_t)b*Ln + (size_t)n*Tn + t)*Cn + co] = hv;   // fp32 h
    }
    __syncthreads();

    if (tid < 96) {
        int r = tid >> 3, o = tid & 7;
        float acc = bk[o];
        for (int ci = 0; ci < Cn; ++ci) {
            int c = (ci + r) & 63;     // rotate: same-address broadcast per r-group
            acc += hs[r*Cn + c] * wkq_s[c*8 + o];
        }
        ((u16*)ws)[U_K + (size_t)b*LP*8 + ((size_t)n*Tn + r)*8 + o] = f2h(acc);
    } else if (tid < 192) {
        int r = (tid - 96) >> 3, o = tid & 7;
        float acc = bq[o] * LOG2E;     // bias scaled to match log2e-scaled wq
        for (int ci = 0; ci < Cn; ++ci) {
            int c = (ci + r) & 63;
            acc += hs[r*Cn + c] * wkq_s[512 + c*8 + o];
        }
        ((u16*)ws)[U_Q + (size_t)b*LP*8 + ((size_t)n*Tn + r)*8 + o] = f2h(acc);
    }
    {
        int jj = tid >> 6, c = tid & 63;
        if (jj < 3) {
            int m = n*Tn + 4*jj;
            int tile = m >> 6, mloc = m & 63;
            int ss = mloc >> 4, q = (mloc >> 2) & 3;
            int cs = c >> 4, rm = c & 15;
            u32 p0 = ((u32)f2h(hs[(4*jj+1)*Cn + c]) << 16) | f2h(hs[(4*jj+0)*Cn + c]);
            u32 p1 = ((u32)f2h(hs[(4*jj+3)*Cn + c]) << 16) | f2h(hs[(4*jj+2)*Cn + c]);
            u16* ht = (u16*)ws + U_HT + (size_t)b*NT*4096
                    + ((tile*16 + ss*4 + cs)*256 + (rm*4 + q)*4);
            *(uint2*)ht = make_uint2(p0, p1);
        }
    }
}

// ---------------- kernel 2: register-fused flash attention -----------------
// 16 q-rows per block (grid 8 x 156 = 1248: occupancy was grid-limited at 832).
// The old 24-row block wasted half of every s1/acc[.][1] MFMA on padding rows;
// dropping that path cuts attn MFMA work 25% and VGPRs by ~16.
// 4 waves, wave w owns tiles {w, w+4, ..., w+36}; wave 3 skips tile 39.
// Pad keys (12, all in tile 38) have k==0 -> e=exp2(0)=1.0 exactly and hT==0,
// so they are computed UNMASKED and the exact constant 12.0 is subtracted
// from the denominator in the epilogue. XCD-affine: b = blockIdx & 7.
__global__ __launch_bounds__(256, 3) void attn_kernel(
    const float* __restrict__ gamma, const float* __restrict__ bv,
    const float* __restrict__ ws, float* __restrict__ out)
{
    __shared__ float part[4*64*16];    // [w][c][r] partial ha, 16 KB
    __shared__ float den_part[4][16];

    int b  = blockIdx.x & 7;           // XCD-affinity swizzle
    int rb = blockIdx.x >> 3;          // 0..155
    int R0 = rb*16;
    int tid = threadIdx.x;
    int lane = tid & 63;
    int w = tid >> 6;                  // 0..3
    int rm = lane & 15;
    int quad = lane >> 4;

    const u16* wsu = (const u16*)ws;
    const u16* kb = wsu + U_K  + (size_t)b*LP*8;
    const u16* qb = wsu + U_Q  + (size_t)b*LP*8;
    const u16* hb = wsu + U_HT + (size_t)b*NT*4096;

    h16x4 qf0;
    {
        uint2 u0 = make_uint2(0, 0);
        int r0 = R0 + rm;
        if (quad < 2)
            u0 = *(const uint2*)(qb + (size_t)r0*8 + 4*quad);
        qf0 = *(h16x4*)&u0;
    }

    const h16x2 one2 = {(h16)1.f, (h16)1.f};

    floatx4 acc[4];
    #pragma unroll
    for (int cs = 0; cs < 4; ++cs) acc[cs] = (floatx4){0.f, 0.f, 0.f, 0.f};
    float dsum0 = 0.f;

    uint2 k0_0,k0_1,k0_2,k0_3, k1_0,k1_1,k1_2,k1_3;
    uint2 h0_0,h0_1,h0_2,h0_3,h0_4,h0_5,h0_6,h0_7,h0_8,h0_9,h0_10,h0_11,h0_12,h0_13,h0_14,h0_15;
    uint2 h1_0,h1_1,h1_2,h1_3,h1_4,h1_5,h1_6,h1_7,h1_8,h1_9,h1_10,h1_11,h1_12,h1_13,h1_14,h1_15;

#define LDK(kt, SS) ((quad < 2) ? *(const uint2*)((kt) + ((SS)*16 + rm)*8 + 4*quad) : make_uint2(0,0))
#define LDH(ht, IDX) (*(const uint2*)((ht) + (IDX)*256 + lane*4))

#define LOADT(B, T) {                                                          \
    int tc = ((T) < NT) ? (T) : (NT-1);                                        \
    const u16* kt_ = kb + (size_t)tc*512;                                      \
    const u16* ht_ = hb + (size_t)tc*4096;                                     \
    k##B##_0 = LDK(kt_, 0); k##B##_1 = LDK(kt_, 1);                            \
    k##B##_2 = LDK(kt_, 2); k##B##_3 = LDK(kt_, 3);                            \
    h##B##_0  = LDH(ht_, 0);  h##B##_1  = LDH(ht_, 1);                         \
    h##B##_2  = LDH(ht_, 2);  h##B##_3  = LDH(ht_, 3);                         \
    h##B##_4  = LDH(ht_, 4);  h##B##_5  = LDH(ht_, 5);                         \
    h##B##_6  = LDH(ht_, 6);  h##B##_7  = LDH(ht_, 7);                         \
    h##B##_8  = LDH(ht_, 8);  h##B##_9  = LDH(ht_, 9);                         \
    h##B##_10 = LDH(ht_, 10); h##B##_11 = LDH(ht_, 11);                        \
    h##B##_12 = LDH(ht_, 12); h##B##_13 = LDH(ht_, 13);                        \
    h##B##_14 = LDH(ht_, 14); h##B##_15 = LDH(ht_, 15);                        \
}

// unmasked softmax-element + PV step; valid for every computed tile (0..38)
#define COMPSS(KR, HA, HB_, HC, HD) {                                          \
    h16x4 kf = *(h16x4*)&KR;                                                   \
    floatx4 s0 = {0.f,0.f,0.f,0.f};                                            \
    s0 = __builtin_amdgcn_mfma_f32_16x16x16f16(kf, qf0, s0, 0, 0, 0);          \
    h16x2 e0a = __builtin_amdgcn_cvt_pkrtz(__builtin_amdgcn_exp2f(s0[0]),      \
                                           __builtin_amdgcn_exp2f(s0[1]));     \
    h16x2 e0b = __builtin_amdgcn_cvt_pkrtz(__builtin_amdgcn_exp2f(s0[2]),      \
                                           __builtin_amdgcn_exp2f(s0[3]));     \
    dsum0 = __builtin_amdgcn_fdot2(e0a, one2, dsum0, false);                   \
    dsum0 = __builtin_amdgcn_fdot2(e0b, one2, dsum0, false);                   \
    h16x4 e0 = __builtin_shufflevector(e0a, e0b, 0, 1, 2, 3);                  \
    h16x4 a0_ = *(h16x4*)&HA, a1_ = *(h16x4*)&HB_, a2_ = *(h16x4*)&HC, a3_ = *(h16x4*)&HD; \
    acc[0] = __builtin_amdgcn_mfma_f32_16x16x16f16(a0_, e0, acc[0], 0, 0, 0);  \
    acc[1] = __builtin_amdgcn_mfma_f32_16x16x16f16(a1_, e0, acc[1], 0, 0, 0);  \
    acc[2] = __builtin_amdgcn_mfma_f32_16x16x16f16(a2_, e0, acc[2], 0, 0, 0);  \
    acc[3] = __builtin_amdgcn_mfma_f32_16x16x16f16(a3_, e0, acc[3], 0, 0, 0);  \
}

#define COMPT(B) {                                                             \
    COMPSS(k##B##_0, h##B##_0,  h##B##_1,  h##B##_2,  h##B##_3)                \
    COMPSS(k##B##_1, h##B##_4,  h##B##_5,  h##B##_6,  h##B##_7)                \
    COMPSS(k##B##_2, h##B##_8,  h##B##_9,  h##B##_10, h##B##_11)               \
    COMPSS(k##B##_3, h##B##_12, h##B##_13, h##B##_14, h##B##_15)               \
}

    LOADT(0, w)
    for (int i = 0; i < 4; ++i) {      // tiles w+8i (buf0) and w+8i+4 (buf1)
        int t0 = w + 8*i;
        LOADT(1, t0 + 4)
        COMPT(0)
        LOADT(0, t0 + 8)
        COMPT(1)
    }
    if (w < 3) LOADT(1, w + 36)        // tiles 36,37,38; wave 3's tile 39 dropped
    COMPT(0)                           // tile w+32
    if (w < 3) COMPT(1)
#undef LOADT
#undef COMPT
#undef COMPSS
#undef LDK
#undef LDH

    {
        float s_ = dsum0;
        s_ += __shfl_xor(s_, 16, 64);
        s_ += __shfl_xor(s_, 32, 64);
        if (quad == 0) den_part[w][rm] = s_;
    }

    float* pw = part + w*1024;
    #pragma unroll
    for (int cs = 0; cs < 4; ++cs)
        #pragma unroll
        for (int i = 0; i < 4; ++i)
            pw[(cs*16 + quad*4 + i)*16 + rm] = acc[cs][i];
    __syncthreads();

    for (int j = tid; j < 1024; j += 256)
        part[j] = part[j] + part[1024 + j] + part[2048 + j] + part[3072 + j];
    __syncthreads();

    int o = tid & 63, rq = tid >> 6;   // rq 0..3, 4 rows each
    float gam = gamma[0];
    float bvo = bv[o];
    const u16* wvr = wsu + U_WVT + o*64;
    uint4 wvu[8];
    #pragma unroll
    for (int x = 0; x < 8; ++x) wvu[x] = *(const uint4*)(wvr + x*8);
    #pragma unroll
    for (int rr = 0; rr < 4; ++rr) {
        int r = rq*4 + rr;
        int row = R0 + r;
        if (row < Ln) {
            // -12.0: remove the 12 zero-key (e==1.0 exact) pad contributions
            float den = den_part[0][r] + den_part[1][r] + den_part[2][r] + den_part[3][r]
                      - 12.0f;
            float p = 0.f;
            #pragma unroll
            for (int x = 0; x < 8; ++x) {
                const f16* hh = (const f16*)&wvu[x];
                #pragma unroll
                for (int i = 0; i < 8; ++i)
                    p += (float)hh[i] * part[(x*8 + i)*16 + r];
            }
            size_t gi = ((size_t)b*Ln + row)*64 + o;
            out[gi] = gam*(bvo + p/den) + out[gi];
        }
    }
}

// ---------------- launch ----------------
extern "C" void kernel_launch(void* const* d_in, const int* in_sizes, int n_in,
                              void* d_out, int out_size, void* d_ws, size_t ws_size,
                              hipStream_t stream) {
    const float* X     = (const float*)d_in[0];
    const float* wA    = (const float*)d_in[1];
    const float* bA    = (const float*)d_in[2];
    const float* wB    = (const float*)d_in[3];
    const float* bB    = (const float*)d_in[4];
    const float* wq    = (const float*)d_in[5];
    const float* bq    = (const float*)d_in[6];
    const float* wk    = (const float*)d_in[7];
    const float* bk    = (const float*)d_in[8];
    const float* wv    = (const float*)d_in[9];
    const float* bv    = (const float*)d_in[10];
    const float* gamma = (const float*)d_in[11];
    float* out = (float*)d_out;
    float* ws  = (float*)d_ws;

    prep_kernel<<<98, 256, 0, stream>>>(wA, wB, wq, wk, wv, ws);
    conv_k_kernel<<<Bn*Nn, 256, 0, stream>>>(X, bA, bB, bk, bq, ws, out);
    attn_kernel<<<Bn*NRB, 256, 0, stream>>>(gamma, bv, ws, out);
}

// Round 8
// 151.469 us; speedup vs baseline: 1.1652x; 1.1652x over previous
//
#include <hip/hip_runtime.h>
#include <hip/hip_bf16.h>

#define Bn 8
#define Nn 207
#define Tn 12
#define Cn 64
#define Ln (Nn*Tn)      // 2484
#define LP 2496         // padded to 64
#define NT 39           // LP/64
#define NRB 156         // 16-row attn blocks per batch (LP/16)

typedef unsigned int u32;
typedef unsigned short u16;
typedef _Float16 f16;
typedef __fp16 h16;
typedef __attribute__((ext_vector_type(2))) __fp16 h16x2;
typedef __attribute__((ext_vector_type(4))) __fp16 h16x4;
typedef __attribute__((ext_vector_type(4))) float floatx4;

#define LOG2E 1.44269504088896f

__device__ __forceinline__ u16 f2h(float f) { f16 h = (f16)f; return *(u16*)&h; }
__device__ __forceinline__ float h2f_lo(u32 u) { u16 x = (u16)u;        f16 h = *(f16*)&x; return (float)h; }
__device__ __forceinline__ float h2f_hi(u32 u) { u16 x = (u16)(u >> 16); f16 h = *(f16*)&x; return (float)h; }

// ---------------- ws layout ----------------
#define W_PW   0            // u32 [k][cig][j][co] packed {wA,wB} : 12288 u32
#define U_WVT  24576        // f16 [o][c] 4096 u16
#define F_WK   14336        // fp32 [c][8] 512 (float offsets)
#define F_WQ   14848        // fp32 [c][8] 512  (pre-scaled by log2(e))
#define U_K    30720        // f16 [Bn][LP][8]   159744 u16 (pad rows zeroed)
#define U_Q    190464       // f16 [Bn][LP][8]   159744 u16 (log2e-scaled q)
// hT swizzled to PV A-frag order: [b][tile][ss][cs][rm*4+quad][i]
#define U_HT   350208       // f16 [Bn][NT][16][256] 1277952 u16 (tail zeroed)

// ---------------- kernel 0: weight pack + pad zeroing ----------
__global__ __launch_bounds__(256) void prep_kernel(
    const float* __restrict__ wA, const float* __restrict__ wB,
    const float* __restrict__ wq, const float* __restrict__ wk,
    const float* __restrict__ wv, float* __restrict__ ws)
{
    u16* wsu = (u16*)ws;
    u32* wsw = (u32*)ws;
    int idx = blockIdx.x * 256 + threadIdx.x;
    if (idx < 12288) {
        int co = idx & 63, j = (idx >> 6) & 7, cig = (idx >> 9) & 7, k = idx >> 12;
        int src = (co*64 + cig*8 + j)*3 + k;
        wsw[W_PW + idx] = (u32)f2h(wA[src]) | ((u32)f2h(wB[src]) << 16);
    } else if (idx < 16384) {
        int j = idx - 12288;
        wsu[U_WVT + j] = f2h(wv[j]);
    } else if (idx < 16896) {
        int j = idx - 16384; int o = j & 7, c = j >> 3;
        ws[F_WK + j] = wk[o*Cn + c];
    } else if (idx < 17408) {
        int j = idx - 16896; int o = j & 7, c = j >> 3;
        ws[F_WQ + j] = wq[o*Cn + c] * LOG2E;      // fold log2(e): exp(s) == exp2(s')
    } else if (idx < 18944) {
        int j = idx - 17408;            // zero k/q pad rows Ln..LP-1
        int b = j / 192, rem = j - b*192;
        int which = rem / 96, rr = rem - which*96;
        wsu[(which ? U_Q : U_K) + (size_t)b*LP*8 + Ln*8 + rr] = 0;
    } else if (idx < 25088) {
        int j = idx - 18944;            // zero hT tail: tile 38, mloc 52..63 (swizzled)
        int b = j / 768, rem = j - b*768;
        int c = rem / 12, mm = 52 + (rem - c*12);
        int ss = mm >> 4, q = (mm >> 2) & 3, i = mm & 3;
        int cs = c >> 4, rm = c & 15;
        wsu[U_HT + (size_t)b*NT*4096 + ((38*16 + ss*4 + cs)*256 + (rm*4 + q)*4 + i)] = 0;
    }
}

// ---------------- kernel 1: conv + GLU + k/q proj + swizzled hT ------------
// one block per (b, n), XCD-affine: b = blockIdx & 7.
// Weights staged in HALVES (cig 0-3 then 4-7): 24 KB buffer instead of 48.
// NOTE: launch_bounds must stay (256,2) — (.,4) force-caps VGPR to 64 and
// spills catastrophically (R4: 305us, R5: 170us, WRITE 446MB).
__global__ __launch_bounds__(256, 2) void conv_k_kernel(
    const float* __restrict__ X,
    const float* __restrict__ bA, const float* __restrict__ bB,
    const float* __restrict__ bk, const float* __restrict__ bq,
    float* __restrict__ ws, float* __restrict__ out)
{
    __shared__ u32   w_s[6144];        // 24 KB: [k][cl(4)][j][co] one cig-half
    __shared__ float xs[Tn*Cn];        // 3 KB
    __shared__ float hs[Tn*Cn];        // 3 KB
    __shared__ float wkq_s[1024];      // 4 KB
    int b = blockIdx.x & 7;            // XCD-affinity swizzle (8 XCDs)
    int n = blockIdx.x >> 3;
    int tid = threadIdx.x;

    const u32* wsw = (const u32*)ws;
    // stage weight half 0 (cig 0..3): 1536 uint4
    #pragma unroll
    for (int i = 0; i < 6; ++i) {
        int d4 = i*256 + tid;
        int co4 = d4 & 15, j = (d4 >> 4) & 7, cl = (d4 >> 7) & 3, k = d4 >> 9;
        ((uint4*)w_s)[d4] = ((const uint4*)(wsw + W_PW))[((k*8 + cl)*8 + j)*16 + co4];
    }
    const float* Xp = X + (size_t)(b*Nn + n)*Tn*Cn;
    if (tid < 192)
        ((float4*)xs)[tid] = ((const float4*)Xp)[tid];
    ((float4*)wkq_s)[tid] = ((const float4*)(ws + F_WK))[tid];
    __syncthreads();                   // half0 + xs ready

    int co = tid & 63;
    int tg = tid >> 6;                 // rows t = 3tg..3tg+2
    float aA[3] = {bA[co], bA[co], bA[co]};
    float aB[3] = {bB[co], bB[co], bB[co]};
    int tb = tg*3 - 2;

    #pragma unroll 1
    for (int half = 0; half < 2; ++half) {
        #pragma unroll 1               // DO NOT unroll: full unroll spills xr -> scratch
        for (int cl = 0; cl < 4; ++cl) {
            int cig = half*4 + cl;
            float xr[5][8];
            #pragma unroll
            for (int d = 0; d < 5; ++d) {
                int tp = tb + d;
                if (tp >= 0) {
                    float4 xa = *(const float4*)(xs + tp*Cn + cig*8);
                    float4 xb = *(const float4*)(xs + tp*Cn + cig*8 + 4);
                    xr[d][0]=xa.x; xr[d][1]=xa.y; xr[d][2]=xa.z; xr[d][3]=xa.w;
                    xr[d][4]=xb.x; xr[d][5]=xb.y; xr[d][6]=xb.z; xr[d][7]=xb.w;
                } else {
                    #pragma unroll
                    for (int j = 0; j < 8; ++j) xr[d][j] = 0.f;
                }
            }
            #pragma unroll
            for (int k = 0; k < 3; ++k) {
                #pragma unroll
                for (int j = 0; j < 8; ++j) {
                    u32 p = w_s[((k*4 + cl)*8 + j)*64 + co];
                    float wa = h2f_lo(p), wb = h2f_hi(p);
                    #pragma unroll
                    for (int tt = 0; tt < 3; ++tt) {
                        aA[tt] += xr[tt + k][j] * wa;
                        aB[tt] += xr[tt + k][j] * wb;
                    }
                }
            }
        }
        if (half == 0) {
            __syncthreads();           // all reads of half0 done
            #pragma unroll
            for (int i = 0; i < 6; ++i) {  // stage half 1 (cig 4..7)
                int d4 = i*256 + tid;
                int co4 = d4 & 15, j = (d4 >> 4) & 7, cl = (d4 >> 7) & 3, k = d4 >> 9;
                ((uint4*)w_s)[d4] =
                    ((const uint4*)(wsw + W_PW))[((k*8 + 4 + cl)*8 + j)*16 + co4];
            }
            __syncthreads();           // half1 ready
        }
    }

    #pragma unroll
    for (int tt = 0; tt < 3; ++tt) {
        int t = tg*3 + tt;
        float hv = aA[tt] * (1.f / (1.f + __expf(-aB[tt])));
        hs[t*Cn + co] = hv;
        out[((size_t)b*Ln + (size_t)n*Tn + t)*Cn + co] = hv;   // fp32 h
    }
    __syncthreads();

    if (tid < 96) {
        int r = tid >> 3, o = tid & 7;
        float acc = bk[o];
        for (int ci = 0; ci < Cn; ++ci) {
            int c = (ci + r) & 63;     // rotate: same-address broadcast per r-group
            acc += hs[r*Cn + c] * wkq_s[c*8 + o];
        }
        ((u16*)ws)[U_K + (size_t)b*LP*8 + ((size_t)n*Tn + r)*8 + o] = f2h(acc);
    } else if (tid < 192) {
        int r = (tid - 96) >> 3, o = tid & 7;
        float acc = bq[o] * LOG2E;     // bias scaled to match log2e-scaled wq
        for (int ci = 0; ci < Cn; ++ci) {
            int c = (ci + r) & 63;
            acc += hs[r*Cn + c] * wkq_s[512 + c*8 + o];
        }
        ((u16*)ws)[U_Q + (size_t)b*LP*8 + ((size_t)n*Tn + r)*8 + o] = f2h(acc);
    }
    {
        int jj = tid >> 6, c = tid & 63;
        if (jj < 3) {
            int m = n*Tn + 4*jj;
            int tile = m >> 6, mloc = m & 63;
            int ss = mloc >> 4, q = (mloc >> 2) & 3;
            int cs = c >> 4, rm = c & 15;
            u32 p0 = ((u32)f2h(hs[(4*jj+1)*Cn + c]) << 16) | f2h(hs[(4*jj+0)*Cn + c]);
            u32 p1 = ((u32)f2h(hs[(4*jj+3)*Cn + c]) << 16) | f2h(hs[(4*jj+2)*Cn + c]);
            u16* ht = (u16*)ws + U_HT + (size_t)b*NT*4096
                    + ((tile*16 + ss*4 + cs)*256 + (rm*4 + q)*4);
            *(uint2*)ht = make_uint2(p0, p1);
        }
    }
}

// ---------------- kernel 2: register-fused flash attention -----------------
// 16 q-rows per block (grid 8 x 156 = 1248). k is double-buffered in regs;
// h (the big 32-VGPR tile) is SINGLE-buffered — R7's h double-buffer pushed
// the kernel over the register cliff (WRITE 55MB scratch spill). The WAR
// hazard on hh also stops the compiler from hoisting all loads.
// 4 waves, wave w owns tiles {w, w+4, ..., w+36}; wave 3 skips tile 39.
// Pad keys (12, all in tile 38) have k==0 -> e=exp2(0)=1.0 exactly and hT==0,
// so they are computed UNMASKED and the exact constant 12.0 is subtracted
// from the denominator in the epilogue. XCD-affine: b = blockIdx & 7.
__global__ __launch_bounds__(256, 3) void attn_kernel(
    const float* __restrict__ gamma, const float* __restrict__ bv,
    const float* __restrict__ ws, float* __restrict__ out)
{
    __shared__ float part[4*64*16];    // [w][c][r] partial ha, 16 KB
    __shared__ float den_part[4][16];

    int b  = blockIdx.x & 7;           // XCD-affinity swizzle
    int rb = blockIdx.x >> 3;          // 0..155
    int R0 = rb*16;
    int tid = threadIdx.x;
    int lane = tid & 63;
    int w = tid >> 6;                  // 0..3
    int rm = lane & 15;
    int quad = lane >> 4;

    const u16* wsu = (const u16*)ws;
    const u16* kb = wsu + U_K  + (size_t)b*LP*8;
    const u16* qb = wsu + U_Q  + (size_t)b*LP*8;
    const u16* hb = wsu + U_HT + (size_t)b*NT*4096;

    h16x4 qf0;
    {
        uint2 u0 = make_uint2(0, 0);
        int r0 = R0 + rm;
        if (quad < 2)
            u0 = *(const uint2*)(qb + (size_t)r0*8 + 4*quad);
        qf0 = *(h16x4*)&u0;
    }

    const h16x2 one2 = {(h16)1.f, (h16)1.f};

    floatx4 acc[4];
    #pragma unroll
    for (int cs = 0; cs < 4; ++cs) acc[cs] = (floatx4){0.f, 0.f, 0.f, 0.f};
    float dsum0 = 0.f;

    uint2 k0_0,k0_1,k0_2,k0_3, k1_0,k1_1,k1_2,k1_3;        // k: double buffer
    uint2 hh_0,hh_1,hh_2,hh_3,hh_4,hh_5,hh_6,hh_7,         // h: SINGLE buffer
          hh_8,hh_9,hh_10,hh_11,hh_12,hh_13,hh_14,hh_15;

#define LDK(kt, SS) ((quad < 2) ? *(const uint2*)((kt) + ((SS)*16 + rm)*8 + 4*quad) : make_uint2(0,0))
#define LDH(ht, IDX) (*(const uint2*)((ht) + (IDX)*256 + lane*4))

#define LOADK(B, T) {                                                          \
    int tc = ((T) < NT) ? (T) : (NT-1);                                        \
    const u16* kt_ = kb + (size_t)tc*512;                                      \
    k##B##_0 = LDK(kt_, 0); k##B##_1 = LDK(kt_, 1);                            \
    k##B##_2 = LDK(kt_, 2); k##B##_3 = LDK(kt_, 3);                            \
}

#define LOADH(T) {                                                             \
    int tc = ((T) < NT) ? (T) : (NT-1);                                        \
    const u16* ht_ = hb + (size_t)tc*4096;                                     \
    hh_0  = LDH(ht_, 0);  hh_1  = LDH(ht_, 1);                                 \
    hh_2  = LDH(ht_, 2);  hh_3  = LDH(ht_, 3);                                 \
    hh_4  = LDH(ht_, 4);  hh_5  = LDH(ht_, 5);                                 \
    hh_6  = LDH(ht_, 6);  hh_7  = LDH(ht_, 7);                                 \
    hh_8  = LDH(ht_, 8);  hh_9  = LDH(ht_, 9);                                 \
    hh_10 = LDH(ht_, 10); hh_11 = LDH(ht_, 11);                                \
    hh_12 = LDH(ht_, 12); hh_13 = LDH(ht_, 13);                                \
    hh_14 = LDH(ht_, 14); hh_15 = LDH(ht_, 15);                                \
}

// unmasked softmax-element + PV step; valid for every computed tile (0..38)
#define COMPSS(KR, HA, HB_, HC, HD) {                                          \
    h16x4 kf = *(h16x4*)&KR;                                                   \
    floatx4 s0 = {0.f,0.f,0.f,0.f};                                            \
    s0 = __builtin_amdgcn_mfma_f32_16x16x16f16(kf, qf0, s0, 0, 0, 0);          \
    h16x2 e0a = __builtin_amdgcn_cvt_pkrtz(__builtin_amdgcn_exp2f(s0[0]),      \
                                           __builtin_amdgcn_exp2f(s0[1]));     \
    h16x2 e0b = __builtin_amdgcn_cvt_pkrtz(__builtin_amdgcn_exp2f(s0[2]),      \
                                           __builtin_amdgcn_exp2f(s0[3]));     \
    dsum0 = __builtin_amdgcn_fdot2(e0a, one2, dsum0, false);                   \
    dsum0 = __builtin_amdgcn_fdot2(e0b, one2, dsum0, false);                   \
    h16x4 e0 = __builtin_shufflevector(e0a, e0b, 0, 1, 2, 3);                  \
    h16x4 a0_ = *(h16x4*)&HA, a1_ = *(h16x4*)&HB_, a2_ = *(h16x4*)&HC, a3_ = *(h16x4*)&HD; \
    acc[0] = __builtin_amdgcn_mfma_f32_16x16x16f16(a0_, e0, acc[0], 0, 0, 0);  \
    acc[1] = __builtin_amdgcn_mfma_f32_16x16x16f16(a1_, e0, acc[1], 0, 0, 0);  \
    acc[2] = __builtin_amdgcn_mfma_f32_16x16x16f16(a2_, e0, acc[2], 0, 0, 0);  \
    acc[3] = __builtin_amdgcn_mfma_f32_16x16x16f16(a3_, e0, acc[3], 0, 0, 0);  \
}

#define COMPT(B) {                                                             \
    __builtin_amdgcn_s_setprio(1);                                             \
    COMPSS(k##B##_0, hh_0,  hh_1,  hh_2,  hh_3)                                \
    COMPSS(k##B##_1, hh_4,  hh_5,  hh_6,  hh_7)                                \
    COMPSS(k##B##_2, hh_8,  hh_9,  hh_10, hh_11)                               \
    COMPSS(k##B##_3, hh_12, hh_13, hh_14, hh_15)                               \
    __builtin_amdgcn_s_setprio(0);                                             \
}

    LOADK(0, w)
    LOADH(w)
    for (int i = 0; i < 4; ++i) {      // tiles w+8i (k buf0) and w+8i+4 (k buf1)
        int t0 = w + 8*i;
        LOADK(1, t0 + 4)
        COMPT(0)                       // tile t0: consumes hh
        LOADH(t0 + 4)                  // refill hh for next tile (WAR after COMPT)
        LOADK(0, t0 + 8)
        COMPT(1)                       // tile t0+4
        LOADH(t0 + 8)
    }
    // tail: tile w+32 (k buf0 + hh already loaded), then w+36 (wave 3's 39 skipped)
    LOADK(1, w + 36)
    COMPT(0)
    if (w < 3) {
        LOADH(w + 36)
        COMPT(1)
    }
#undef LOADK
#undef LOADH
#undef COMPT
#undef COMPSS
#undef LDK
#undef LDH

    {
        float s_ = dsum0;
        s_ += __shfl_xor(s_, 16, 64);
        s_ += __shfl_xor(s_, 32, 64);
        if (quad == 0) den_part[w][rm] = s_;
    }

    float* pw = part + w*1024;
    #pragma unroll
    for (int cs = 0; cs < 4; ++cs)
        #pragma unroll
        for (int i = 0; i < 4; ++i)
            pw[(cs*16 + quad*4 + i)*16 + rm] = acc[cs][i];
    __syncthreads();

    for (int j = tid; j < 1024; j += 256)
        part[j] = part[j] + part[1024 + j] + part[2048 + j] + part[3072 + j];
    __syncthreads();

    int o = tid & 63, rq = tid >> 6;   // rq 0..3, 4 rows each
    float gam = gamma[0];
    float bvo = bv[o];
    const u16* wvr = wsu + U_WVT + o*64;
    uint4 wvu[8];
    #pragma unroll
    for (int x = 0; x < 8; ++x) wvu[x] = *(const uint4*)(wvr + x*8);
    #pragma unroll
    for (int rr = 0; rr < 4; ++rr) {
        int r = rq*4 + rr;
        int row = R0 + r;
        if (row < Ln) {
            // -12.0: remove the 12 zero-key (e==1.0 exact) pad contributions
            float den = den_part[0][r] + den_part[1][r] + den_part[2][r] + den_part[3][r]
                      - 12.0f;
            float p = 0.f;
            #pragma unroll
            for (int x = 0; x < 8; ++x) {
                const f16* hh = (const f16*)&wvu[x];
                #pragma unroll
                for (int i = 0; i < 8; ++i)
                    p += (float)hh[i] * part[(x*8 + i)*16 + r];
            }
            size_t gi = ((size_t)b*Ln + row)*64 + o;
            out[gi] = gam*(bvo + p/den) + out[gi];
        }
    }
}

// ---------------- launch ----------------
extern "C" void kernel_launch(void* const* d_in, const int* in_sizes, int n_in,
                              void* d_out, int out_size, void* d_ws, size_t ws_size,
                              hipStream_t stream) {
    const float* X     = (const float*)d_in[0];
    const float* wA    = (const float*)d_in[1];
    const float* bA    = (const float*)d_in[2];
    const float* wB    = (const float*)d_in[3];
    const float* bB    = (const float*)d_in[4];
    const float* wq    = (const float*)d_in[5];
    const float* bq    = (const float*)d_in[6];
    const float* wk    = (const float*)d_in[7];
    const float* bk    = (const float*)d_in[8];
    const float* wv    = (const float*)d_in[9];
    const float* bv    = (const float*)d_in[10];
    const float* gamma = (const float*)d_in[11];
    float* out = (float*)d_out;
    float* ws  = (float*)d_ws;

    prep_kernel<<<98, 256, 0, stream>>>(wA, wB, wq, wk, wv, ws);
    conv_k_kernel<<<Bn*Nn, 256, 0, stream>>>(X, bA, bB, bk, bq, ws, out);
    attn_kernel<<<Bn*NRB, 256, 0, stream>>>(gamma, bv, ws, out);
}

// Round 9
// 142.073 us; speedup vs baseline: 1.2422x; 1.0661x over previous
//
#include <hip/hip_runtime.h>
#include <hip/hip_bf16.h>

#define Bn 8
#define Nn 207
#define Tn 12
#define Cn 64
#define Ln (Nn*Tn)      // 2484
#define LP 2496         // padded to 64
#define NT 39           // LP/64
#define NRB 156         // 16-row attn blocks per batch (LP/16)

typedef unsigned int u32;
typedef unsigned short u16;
typedef _Float16 f16;
typedef __fp16 h16;
typedef __attribute__((ext_vector_type(2))) __fp16 h16x2;
typedef __attribute__((ext_vector_type(4))) __fp16 h16x4;
typedef __attribute__((ext_vector_type(4))) float floatx4;

#define LOG2E 1.44269504088896f

__device__ __forceinline__ u16 f2h(float f) { f16 h = (f16)f; return *(u16*)&h; }
__device__ __forceinline__ float h2f_lo(u32 u) { u16 x = (u16)u;        f16 h = *(f16*)&x; return (float)h; }
__device__ __forceinline__ float h2f_hi(u32 u) { u16 x = (u16)(u >> 16); f16 h = *(f16*)&x; return (float)h; }

// ---------------- ws layout ----------------
#define W_PW   0            // u32 [k][cig][j][co] packed {wA,wB} : 12288 u32
#define U_WVT  24576        // f16 [o][c] 4096 u16
#define F_WK   14336        // fp32 [c][8] 512 (float offsets)
#define F_WQ   14848        // fp32 [c][8] 512  (pre-scaled by log2(e))
#define U_K    30720        // f16 [Bn][LP][8]   159744 u16 (pad rows zeroed)
#define U_Q    190464       // f16 [Bn][LP][8]   159744 u16 (log2e-scaled q)
// hT PAIRED PV A-frag order: [b][tile][pair(8)][lane(64)][8]
//   pair P, lane L: u16 0-3 = fragment idx 2P, u16 4-7 = fragment idx 2P+1
#define U_HT   350208       // f16 [Bn][NT][4096] 1277952 u16 (tail zeroed)

// ---------------- kernel 0: weight pack + pad zeroing ----------
__global__ __launch_bounds__(256) void prep_kernel(
    const float* __restrict__ wA, const float* __restrict__ wB,
    const float* __restrict__ wq, const float* __restrict__ wk,
    const float* __restrict__ wv, float* __restrict__ ws)
{
    u16* wsu = (u16*)ws;
    u32* wsw = (u32*)ws;
    int idx = blockIdx.x * 256 + threadIdx.x;
    if (idx < 12288) {
        int co = idx & 63, j = (idx >> 6) & 7, cig = (idx >> 9) & 7, k = idx >> 12;
        int src = (co*64 + cig*8 + j)*3 + k;
        wsw[W_PW + idx] = (u32)f2h(wA[src]) | ((u32)f2h(wB[src]) << 16);
    } else if (idx < 16384) {
        int j = idx - 12288;
        wsu[U_WVT + j] = f2h(wv[j]);
    } else if (idx < 16896) {
        int j = idx - 16384; int o = j & 7, c = j >> 3;
        ws[F_WK + j] = wk[o*Cn + c];
    } else if (idx < 17408) {
        int j = idx - 16896; int o = j & 7, c = j >> 3;
        ws[F_WQ + j] = wq[o*Cn + c] * LOG2E;      // fold log2(e): exp(s) == exp2(s')
    } else if (idx < 18944) {
        int j = idx - 17408;            // zero k/q pad rows Ln..LP-1
        int b = j / 192, rem = j - b*192;
        int which = rem / 96, rr = rem - which*96;
        wsu[(which ? U_Q : U_K) + (size_t)b*LP*8 + Ln*8 + rr] = 0;
    } else if (idx < 25088) {
        int j = idx - 18944;            // zero hT tail: tile 38, mloc 52..63 (paired)
        int b = j / 768, rem = j - b*768;
        int c = rem / 12, mm = 52 + (rem - c*12);
        int ss = mm >> 4, q = (mm >> 2) & 3, i = mm & 3;
        int cs = c >> 4, rm = c & 15;
        int fidx = ss*4 + cs;           // fragment index 0..15
        wsu[U_HT + (size_t)b*NT*4096 + 38*4096
            + (fidx >> 1)*512 + (rm*4 + q)*8 + (fidx & 1)*4 + i] = 0;
    }
}

// ---------------- kernel 1: conv + GLU + k/q proj + paired hT --------------
// one block per (b, n), XCD-affine: b = blockIdx & 7.
// Weights staged in HALVES (cig 0-3 then 4-7): 24 KB buffer instead of 48.
// NOTE: launch_bounds must stay (256,2) — (.,4) force-caps VGPR to 64 and
// spills catastrophically (R4: 305us, R5: 170us, WRITE 446MB).
__global__ __launch_bounds__(256, 2) void conv_k_kernel(
    const float* __restrict__ X,
    const float* __restrict__ bA, const float* __restrict__ bB,
    const float* __restrict__ bk, const float* __restrict__ bq,
    float* __restrict__ ws, float* __restrict__ out)
{
    __shared__ u32   w_s[6144];        // 24 KB: [k][cl(4)][j][co] one cig-half
    __shared__ float xs[Tn*Cn];        // 3 KB
    __shared__ float hs[Tn*Cn];        // 3 KB
    __shared__ float wkq_s[1024];      // 4 KB
    int b = blockIdx.x & 7;            // XCD-affinity swizzle (8 XCDs)
    int n = blockIdx.x >> 3;
    int tid = threadIdx.x;

    const u32* wsw = (const u32*)ws;
    // stage weight half 0 (cig 0..3): 1536 uint4
    #pragma unroll
    for (int i = 0; i < 6; ++i) {
        int d4 = i*256 + tid;
        int co4 = d4 & 15, j = (d4 >> 4) & 7, cl = (d4 >> 7) & 3, k = d4 >> 9;
        ((uint4*)w_s)[d4] = ((const uint4*)(wsw + W_PW))[((k*8 + cl)*8 + j)*16 + co4];
    }
    const float* Xp = X + (size_t)(b*Nn + n)*Tn*Cn;
    if (tid < 192)
        ((float4*)xs)[tid] = ((const float4*)Xp)[tid];
    ((float4*)wkq_s)[tid] = ((const float4*)(ws + F_WK))[tid];
    __syncthreads();                   // half0 + xs ready

    int co = tid & 63;
    int tg = tid >> 6;                 // rows t = 3tg..3tg+2
    float aA[3] = {bA[co], bA[co], bA[co]};
    float aB[3] = {bB[co], bB[co], bB[co]};
    int tb = tg*3 - 2;

    #pragma unroll 1
    for (int half = 0; half < 2; ++half) {
        #pragma unroll 1               // DO NOT unroll: full unroll spills xr -> scratch
        for (int cl = 0; cl < 4; ++cl) {
            int cig = half*4 + cl;
            float xr[5][8];
            #pragma unroll
            for (int d = 0; d < 5; ++d) {
                int tp = tb + d;
                if (tp >= 0) {
                    float4 xa = *(const float4*)(xs + tp*Cn + cig*8);
                    float4 xb = *(const float4*)(xs + tp*Cn + cig*8 + 4);
                    xr[d][0]=xa.x; xr[d][1]=xa.y; xr[d][2]=xa.z; xr[d][3]=xa.w;
                    xr[d][4]=xb.x; xr[d][5]=xb.y; xr[d][6]=xb.z; xr[d][7]=xb.w;
                } else {
                    #pragma unroll
                    for (int j = 0; j < 8; ++j) xr[d][j] = 0.f;
                }
            }
            #pragma unroll
            for (int k = 0; k < 3; ++k) {
                #pragma unroll
                for (int j = 0; j < 8; ++j) {
                    u32 p = w_s[((k*4 + cl)*8 + j)*64 + co];
                    float wa = h2f_lo(p), wb = h2f_hi(p);
                    #pragma unroll
                    for (int tt = 0; tt < 3; ++tt) {
                        aA[tt] += xr[tt + k][j] * wa;
                        aB[tt] += xr[tt + k][j] * wb;
                    }
                }
            }
        }
        if (half == 0) {
            __syncthreads();           // all reads of half0 done
            #pragma unroll
            for (int i = 0; i < 6; ++i) {  // stage half 1 (cig 4..7)
                int d4 = i*256 + tid;
                int co4 = d4 & 15, j = (d4 >> 4) & 7, cl = (d4 >> 7) & 3, k = d4 >> 9;
                ((uint4*)w_s)[d4] =
                    ((const uint4*)(wsw + W_PW))[((k*8 + 4 + cl)*8 + j)*16 + co4];
            }
            __syncthreads();           // half1 ready
        }
    }

    #pragma unroll
    for (int tt = 0; tt < 3; ++tt) {
        int t = tg*3 + tt;
        float hv = aA[tt] * (1.f / (1.f + __expf(-aB[tt])));
        hs[t*Cn + co] = hv;
        out[((size_t)b*Ln + (size_t)n*Tn + t)*Cn + co] = hv;   // fp32 h
    }
    __syncthreads();

    if (tid < 96) {
        int r = tid >> 3, o = tid & 7;
        float acc = bk[o];
        for (int ci = 0; ci < Cn; ++ci) {
            int c = (ci + r) & 63;     // rotate: same-address broadcast per r-group
            acc += hs[r*Cn + c] * wkq_s[c*8 + o];
        }
        ((u16*)ws)[U_K + (size_t)b*LP*8 + ((size_t)n*Tn + r)*8 + o] = f2h(acc);
    } else if (tid < 192) {
        int r = (tid - 96) >> 3, o = tid & 7;
        float acc = bq[o] * LOG2E;     // bias scaled to match log2e-scaled wq
        for (int ci = 0; ci < Cn; ++ci) {
            int c = (ci + r) & 63;
            acc += hs[r*Cn + c] * wkq_s[512 + c*8 + o];
        }
        ((u16*)ws)[U_Q + (size_t)b*LP*8 + ((size_t)n*Tn + r)*8 + o] = f2h(acc);
    }
    {
        int jj = tid >> 6, c = tid & 63;
        if (jj < 3) {
            int m = n*Tn + 4*jj;
            int tile = m >> 6, mloc = m & 63;
            int ss = mloc >> 4, q = (mloc >> 2) & 3;
            int cs = c >> 4, rm = c & 15;
            u32 p0 = ((u32)f2h(hs[(4*jj+1)*Cn + c]) << 16) | f2h(hs[(4*jj+0)*Cn + c]);
            u32 p1 = ((u32)f2h(hs[(4*jj+3)*Cn + c]) << 16) | f2h(hs[(4*jj+2)*Cn + c]);
            int fidx = ss*4 + cs;      // fragment index; paired layout
            u16* ht = (u16*)ws + U_HT + (size_t)b*NT*4096 + tile*4096
                    + (fidx >> 1)*512 + (rm*4 + q)*8 + (fidx & 1)*4;
            *(uint2*)ht = make_uint2(p0, p1);
        }
    }
}

// ---------------- kernel 2: register-fused flash attention -----------------
// 16 q-rows per block (grid 8 x 156 = 1248). k double-buffered; h SINGLE-
// buffered as 8 uint4 (paired fragments: one 16B load = 2 PV A-frags,
// 12 loads/tile instead of 20). R7 showed h double-buffering spills.
// 4 waves, wave w owns tiles {w, w+4, ..., w+36}; wave 3 skips tile 39.
// Pad keys (12, all in tile 38) have k==0 -> e=exp2(0)=1.0 exactly and hT==0,
// so they are computed UNMASKED and the exact constant 12.0 is subtracted
// from the denominator in the epilogue. XCD-affine: b = blockIdx & 7.
__global__ __launch_bounds__(256, 3) void attn_kernel(
    const float* __restrict__ gamma, const float* __restrict__ bv,
    const float* __restrict__ ws, float* __restrict__ out)
{
    __shared__ float part[4*64*16];    // [w][c][r] partial ha, 16 KB
    __shared__ float den_part[4][16];

    int b  = blockIdx.x & 7;           // XCD-affinity swizzle
    int rb = blockIdx.x >> 3;          // 0..155
    int R0 = rb*16;
    int tid = threadIdx.x;
    int lane = tid & 63;
    int w = tid >> 6;                  // 0..3
    int rm = lane & 15;
    int quad = lane >> 4;

    const u16* wsu = (const u16*)ws;
    const u16* kb = wsu + U_K  + (size_t)b*LP*8;
    const u16* qb = wsu + U_Q  + (size_t)b*LP*8;
    const u16* hb = wsu + U_HT + (size_t)b*NT*4096;

    h16x4 qf0;
    {
        uint2 u0 = make_uint2(0, 0);
        int r0 = R0 + rm;
        if (quad < 2)
            u0 = *(const uint2*)(qb + (size_t)r0*8 + 4*quad);
        qf0 = *(h16x4*)&u0;
    }

    const h16x2 one2 = {(h16)1.f, (h16)1.f};

    floatx4 acc[4];
    #pragma unroll
    for (int cs = 0; cs < 4; ++cs) acc[cs] = (floatx4){0.f, 0.f, 0.f, 0.f};
    float dsum0 = 0.f;

    uint2 k0_0,k0_1,k0_2,k0_3, k1_0,k1_1,k1_2,k1_3;        // k: double buffer
    uint4 hp_0,hp_1,hp_2,hp_3,hp_4,hp_5,hp_6,hp_7;         // h: single, paired

#define LDK(kt, SS) ((quad < 2) ? *(const uint2*)((kt) + ((SS)*16 + rm)*8 + 4*quad) : make_uint2(0,0))
#define LDH4(ht, P) (*(const uint4*)((ht) + (P)*512 + lane*8))

#define LOADK(B, T) {                                                          \
    int tc = ((T) < NT) ? (T) : (NT-1);                                        \
    const u16* kt_ = kb + (size_t)tc*512;                                      \
    k##B##_0 = LDK(kt_, 0); k##B##_1 = LDK(kt_, 1);                            \
    k##B##_2 = LDK(kt_, 2); k##B##_3 = LDK(kt_, 3);                            \
}

#define LOADH(T) {                                                             \
    int tc = ((T) < NT) ? (T) : (NT-1);                                        \
    const u16* ht_ = hb + (size_t)tc*4096;                                     \
    hp_0 = LDH4(ht_, 0); hp_1 = LDH4(ht_, 1);                                  \
    hp_2 = LDH4(ht_, 2); hp_3 = LDH4(ht_, 3);                                  \
    hp_4 = LDH4(ht_, 4); hp_5 = LDH4(ht_, 5);                                  \
    hp_6 = LDH4(ht_, 6); hp_7 = LDH4(ht_, 7);                                  \
}

// unmasked softmax-element + PV step; PA holds frags {2ss, 2ss+1}... i.e.
// COMPSS(ss) consumes pairs 2ss (frags 4ss,4ss+1) and 2ss+1 (frags 4ss+2,4ss+3)
#define COMPSS(KR, PA, PB) {                                                   \
    h16x4 kf = *(h16x4*)&KR;                                                   \
    floatx4 s0 = {0.f,0.f,0.f,0.f};                                            \
    s0 = __builtin_amdgcn_mfma_f32_16x16x16f16(kf, qf0, s0, 0, 0, 0);          \
    h16x2 e0a = __builtin_amdgcn_cvt_pkrtz(__builtin_amdgcn_exp2f(s0[0]),      \
                                           __builtin_amdgcn_exp2f(s0[1]));     \
    h16x2 e0b = __builtin_amdgcn_cvt_pkrtz(__builtin_amdgcn_exp2f(s0[2]),      \
                                           __builtin_amdgcn_exp2f(s0[3]));     \
    dsum0 = __builtin_amdgcn_fdot2(e0a, one2, dsum0, false);                   \
    dsum0 = __builtin_amdgcn_fdot2(e0b, one2, dsum0, false);                   \
    h16x4 e0 = __builtin_shufflevector(e0a, e0b, 0, 1, 2, 3);                  \
    h16x4 a0_ = *(h16x4*)&PA.x, a1_ = *(h16x4*)&PA.z;                          \
    h16x4 a2_ = *(h16x4*)&PB.x, a3_ = *(h16x4*)&PB.z;                          \
    acc[0] = __builtin_amdgcn_mfma_f32_16x16x16f16(a0_, e0, acc[0], 0, 0, 0);  \
    acc[1] = __builtin_amdgcn_mfma_f32_16x16x16f16(a1_, e0, acc[1], 0, 0, 0);  \
    acc[2] = __builtin_amdgcn_mfma_f32_16x16x16f16(a2_, e0, acc[2], 0, 0, 0);  \
    acc[3] = __builtin_amdgcn_mfma_f32_16x16x16f16(a3_, e0, acc[3], 0, 0, 0);  \
}

#define COMPT(B) {                                                             \
    __builtin_amdgcn_s_setprio(1);                                             \
    COMPSS(k##B##_0, hp_0, hp_1)                                               \
    COMPSS(k##B##_1, hp_2, hp_3)                                               \
    COMPSS(k##B##_2, hp_4, hp_5)                                               \
    COMPSS(k##B##_3, hp_6, hp_7)                                               \
    __builtin_amdgcn_s_setprio(0);                                             \
}

    LOADK(0, w)
    LOADH(w)
    for (int i = 0; i < 4; ++i) {      // tiles w+8i (k buf0) and w+8i+4 (k buf1)
        int t0 = w + 8*i;
        LOADK(1, t0 + 4)
        COMPT(0)                       // tile t0: consumes hp
        LOADH(t0 + 4)                  // refill hp for next tile (WAR after COMPT)
        LOADK(0, t0 + 8)
        COMPT(1)                       // tile t0+4
        LOADH(t0 + 8)
    }
    // tail: tile w+32 (k buf0 + hp already loaded), then w+36 (wave 3's 39 skipped)
    LOADK(1, w + 36)
    COMPT(0)
    if (w < 3) {
        LOADH(w + 36)
        COMPT(1)
    }
#undef LOADK
#undef LOADH
#undef COMPT
#undef COMPSS
#undef LDK
#undef LDH4

    {
        float s_ = dsum0;
        s_ += __shfl_xor(s_, 16, 64);
        s_ += __shfl_xor(s_, 32, 64);
        if (quad == 0) den_part[w][rm] = s_;
    }

    float* pw = part + w*1024;
    #pragma unroll
    for (int cs = 0; cs < 4; ++cs)
        #pragma unroll
        for (int i = 0; i < 4; ++i)
            pw[(cs*16 + quad*4 + i)*16 + rm] = acc[cs][i];
    __syncthreads();

    for (int j = tid; j < 1024; j += 256)
        part[j] = part[j] + part[1024 + j] + part[2048 + j] + part[3072 + j];
    __syncthreads();

    int o = tid & 63, rq = tid >> 6;   // rq 0..3, 4 rows each
    float gam = gamma[0];
    float bvo = bv[o];
    const u16* wvr = wsu + U_WVT + o*64;
    uint4 wvu[8];
    #pragma unroll
    for (int x = 0; x < 8; ++x) wvu[x] = *(const uint4*)(wvr + x*8);
    #pragma unroll
    for (int rr = 0; rr < 4; ++rr) {
        int r = rq*4 + rr;
        int row = R0 + r;
        if (row < Ln) {
            // -12.0: remove the 12 zero-key (e==1.0 exact) pad contributions
            float den = den_part[0][r] + den_part[1][r] + den_part[2][r] + den_part[3][r]
                      - 12.0f;
            float p = 0.f;
            #pragma unroll
            for (int x = 0; x < 8; ++x) {
                const f16* hh = (const f16*)&wvu[x];
                #pragma unroll
                for (int i = 0; i < 8; ++i)
                    p += (float)hh[i] * part[(x*8 + i)*16 + r];
            }
            size_t gi = ((size_t)b*Ln + row)*64 + o;
            out[gi] = gam*(bvo + p/den) + out[gi];
        }
    }
}

// ---------------- launch ----------------
extern "C" void kernel_launch(void* const* d_in, const int* in_sizes, int n_in,
                              void* d_out, int out_size, void* d_ws, size_t ws_size,
                              hipStream_t stream) {
    const float* X     = (const float*)d_in[0];
    const float* wA    = (const float*)d_in[1];
    const float* bA    = (const float*)d_in[2];
    const float* wB    = (const float*)d_in[3];
    const float* bB    = (const float*)d_in[4];
    const float* wq    = (const float*)d_in[5];
    const float* bq    = (const float*)d_in[6];
    const float* wk    = (const float*)d_in[7];
    const float* bk    = (const float*)d_in[8];
    const float* wv    = (const float*)d_in[9];
    const float* bv    = (const float*)d_in[10];
    const float* gamma = (const float*)d_in[11];
    float* out = (float*)d_out;
    float* ws  = (float*)d_ws;

    prep_kernel<<<98, 256, 0, stream>>>(wA, wB, wq, wk, wv, ws);
    conv_k_kernel<<<Bn*Nn, 256, 0, stream>>>(X, bA, bB, bk, bq, ws, out);
    attn_kernel<<<Bn*NRB, 256, 0, stream>>>(gamma, bv, ws, out);
}